// Round 4
// baseline (582.662 us; speedup 1.0000x reference)
//
#include <hip/hip_runtime.h>
#include <hip/hip_bf16.h>

// ---------- helpers ----------
typedef __attribute__((ext_vector_type(8))) __bf16 bf16x8;
typedef __attribute__((ext_vector_type(4))) float f32x4;

__device__ __forceinline__ float b2f(unsigned short u) {
    unsigned int x = ((unsigned int)u) << 16;
    float f;
    __builtin_memcpy(&f, &x, 4);
    return f;
}
__device__ __forceinline__ unsigned short f2b(float f) {
    __hip_bfloat16 h = __float2bfloat16(f);
    unsigned short u;
    __builtin_memcpy(&u, &h, 2);
    return u;
}
union U4 { uint4 v; unsigned short u[8]; };

// ---------- 4x fused 512x512 transpose + f32->bf16 convert (W matrices) ----------
__global__ __launch_bounds__(256) void transpose512cvt4(
    const float* __restrict__ i0, const float* __restrict__ i1,
    const float* __restrict__ i2, const float* __restrict__ i3,
    unsigned short* __restrict__ o0, unsigned short* __restrict__ o1,
    unsigned short* __restrict__ o2, unsigned short* __restrict__ o3)
{
    const float* in = i0;
    unsigned short* out = o0;
    if (blockIdx.z == 1) { in = i1; out = o1; }
    else if (blockIdx.z == 2) { in = i2; out = o2; }
    else if (blockIdx.z == 3) { in = i3; out = o3; }
    __shared__ float tile[32][33];
    int tx = threadIdx.x & 31, ty = threadIdx.x >> 5;
    int bx = blockIdx.x, by = blockIdx.y;
    #pragma unroll
    for (int i = 0; i < 32; i += 8)
        tile[ty + i][tx] = in[(size_t)(bx * 32 + ty + i) * 512 + by * 32 + tx];
    __syncthreads();
    #pragma unroll
    for (int i = 0; i < 32; i += 8)
        out[(size_t)(by * 32 + ty + i) * 512 + bx * 32 + tx] = f2b(tile[tx][ty + i]);
}

// ---------- GEMM v3: B-panel-persistent, near-barrier-free ----------
// C[M,512] = A[M,512] @ Bt[512,512]^T + bias.  Block = 8 waves, owns one
// 128-col n-panel and 512 m-rows (8 waves x 64 rows).  B panel staged in LDS
// in two 256-K halves (64 KB, XOR-swizzled -> conflict-free ds_read_b128);
// only 4 barriers per block.  Between barriers waves run fully independent:
// A fragments straight from global (1-step register prefetch, f32->bf16 cvt
// in flight), 32 MFMA per K-step into a 64x128 register tile.
// Bijective XCD pack: the 4 n-panel blocks sharing an A m-group get blockIdx
// differing by 8 -> same XCD -> A re-reads are L2 hits (A HBM-read = once).
// cmode: 0 = f32 token-major, 1 = bf16 token-major, 2 = bf16 head-major.

struct GemmSet {
    const void* A;
    const unsigned short* B;
    const float* bias;
    void* C;
    int cmode;
};

template<bool AF32>
__global__ __launch_bounds__(512, 2) void gemm_bp(
    GemmSet s0, GemmSet s1, GemmSet s2, int M, int mgroups)
{
    const int K = 512, N = 512;
    __shared__ __align__(16) unsigned short Bs[128 * 256];  // 64 KB, swizzled

    int NB = gridDim.x, bid = blockIdx.x;
    int wid;
    if ((NB & 31) == 0) {
        int x = bid & 7, tt = bid >> 3, r = tt & 3, j = tt >> 2;
        wid = (j * 8 + x) * 4 + r;     // same (gemm,mgroup) -> bids differ by 8
    } else wid = bid;
    int q = wid >> 2, np = wid & 3;
    int g = q / mgroups, mg = q - g * mgroups;
    GemmSet S = (g == 0) ? s0 : ((g == 1) ? s1 : s2);
    int n0 = np * 128, m0 = mg * 512;

    int t = threadIdx.x;
    int w = t >> 6, lane = t & 63, quad = lane >> 4, l16 = lane & 15;
    bool active = (m0 + w * 64) < M;
    size_t mrow = (size_t)(m0 + w * 64 + l16);

    const float* Ap32 = (const float*)S.A + mrow * K + quad * 8;
    const unsigned short* Ap16 = (const unsigned short*)S.A + mrow * K + quad * 8;

    // B staging coords: thread t -> row t>>2, 64-elem segment t&3 (per K-half)
    int srow = t >> 2, sseg = t & 3;
    const unsigned short* Bg = S.B + (size_t)(n0 + srow) * K + sseg * 64;
    char* Bsb = (char*)Bs;
    unsigned int wbase = ((unsigned int)srow << 9) + ((unsigned int)sseg << 7);
    unsigned int wxor = ((unsigned int)(srow & 7)) << 4;
    unsigned int rxor = ((unsigned int)(l16 & 7)) << 4;

    f32x4 acc[4][8];
    #pragma unroll
    for (int i = 0; i < 4; ++i)
        #pragma unroll
        for (int j = 0; j < 8; ++j) acc[i][j] = (f32x4){0.f, 0.f, 0.f, 0.f};

    float4 pf[8];   // AF32 prefetch (4 frags x 32 B)
    uint4 ph[4];    // bf16 prefetch (4 frags x 16 B)

    auto ALOAD = [&](int kk) {
        if constexpr (AF32) {
            #pragma unroll
            for (int i = 0; i < 4; ++i) {
                const float4* pp = (const float4*)(Ap32 + (size_t)i * 16 * K + kk);
                pf[2 * i] = pp[0]; pf[2 * i + 1] = pp[1];
            }
        } else {
            #pragma unroll
            for (int i = 0; i < 4; ++i)
                ph[i] = *(const uint4*)(Ap16 + (size_t)i * 16 * K + kk);
        }
    };
    auto ACVT = [&](bf16x8* af) {
        if constexpr (AF32) {
            #pragma unroll
            for (int i = 0; i < 4; ++i) {
                U4 u;
                u.u[0] = f2b(pf[2*i].x);   u.u[1] = f2b(pf[2*i].y);
                u.u[2] = f2b(pf[2*i].z);   u.u[3] = f2b(pf[2*i].w);
                u.u[4] = f2b(pf[2*i+1].x); u.u[5] = f2b(pf[2*i+1].y);
                u.u[6] = f2b(pf[2*i+1].z); u.u[7] = f2b(pf[2*i+1].w);
                af[i] = *(bf16x8*)&u;
            }
        } else {
            #pragma unroll
            for (int i = 0; i < 4; ++i) af[i] = *(bf16x8*)&ph[i];
        }
    };
    auto STAGE = [&](int p) {
        uint4 v[8];
        #pragma unroll
        for (int i = 0; i < 8; ++i)
            v[i] = *(const uint4*)(Bg + p * 256 + i * 8);
        #pragma unroll
        for (int i = 0; i < 8; ++i)
            *(uint4*)(Bsb + ((wbase + i * 16) ^ wxor)) = v[i];
    };

    if (active) ALOAD(0);
    #pragma unroll
    for (int p = 0; p < 2; ++p) {
        __syncthreads();              // prior-phase LDS reads done
        STAGE(p);
        __syncthreads();              // B half ready
        if (active) {
            int kb = p * 256;
            for (int ks = 0; ks < 8; ++ks) {
                bf16x8 af[4];
                ACVT(af);
                if (ks < 7) ALOAD(kb + (ks + 1) * 32);
                else if (p == 0) ALOAD(256);      // cross-half prefetch
                unsigned int kl2b = (unsigned int)((ks * 32 + quad * 8) * 2);
                #pragma unroll
                for (int j = 0; j < 8; ++j) {
                    unsigned int rb = (((unsigned int)(j * 16 + l16)) << 9) + kl2b;
                    bf16x8 bf = *(const bf16x8*)(Bsb + (rb ^ rxor));
                    #pragma unroll
                    for (int i = 0; i < 4; ++i)
                        acc[i][j] = __builtin_amdgcn_mfma_f32_16x16x32_bf16(af[i], bf, acc[i][j], 0, 0, 0);
                }
            }
        }
    }

    if (!active) return;
    // epilogue. C/D layout: col = lane&15, row = quad*4 + reg
    int cmode = S.cmode;
    #pragma unroll
    for (int j = 0; j < 8; ++j) {
        int col = n0 + j * 16 + l16;
        float bc = S.bias[col];
        #pragma unroll
        for (int i = 0; i < 4; ++i) {
            int row = m0 + w * 64 + i * 16 + quad * 4;
            #pragma unroll
            for (int ii = 0; ii < 4; ++ii) {
                float v = acc[i][j][ii] + bc;
                int R = row + ii;
                if (cmode == 0) {
                    ((float*)S.C)[(size_t)R * N + col] = v;
                } else if (cmode == 1) {
                    ((unsigned short*)S.C)[(size_t)R * N + col] = f2b(v);
                } else {
                    int bb = R >> 12, n = R & 4095, hh = col >> 6, d = col & 63;
                    ((unsigned short*)S.C)[(((size_t)bb * 8 + hh) * 4096 + n) * 64 + d] = f2b(v);
                }
            }
        }
    }
}

// ---------- temporal attention v2: MFMA, one block per (b, s-pair), 8 waves = 8 heads ----------
__global__ __launch_bounds__(512) void temporal_attn(
    const unsigned short* __restrict__ Qt, const unsigned short* __restrict__ KH,
    const unsigned short* __restrict__ VH, const unsigned short* __restrict__ Ksp,
    const unsigned short* __restrict__ Vsp,
    const int* __restrict__ mask_t, const int* __restrict__ mask_s,
    float* __restrict__ w_t_out, unsigned short* __restrict__ qkv_t)
{
    int blk = blockIdx.x;              // b*256 + sp
    int b = blk >> 8, sp = blk & 255;
    int s0 = sp * 2;
    int t = threadIdx.x;
    int h = t >> 6, lane = t & 63, quad = lane >> 4, l16 = lane & 15;

    __shared__ __align__(16) unsigned short Vt[8][64 * 40];  // per-head V^T [d][key(32)+pad]
    __shared__ __align__(16) unsigned short Pl[8][16 * 40];  // per-head P  [q][key(32)+pad]

    size_t bh = (size_t)(b * 8 + h);
    size_t tok0 = ((size_t)(b * 512 + s0)) * 8;

    // ---- stage V^T (wave-private; keys 0-15 temporal, 16-31 static) ----
    {
        int r = lane & 31, dh = (lane >> 5) * 32;
        const unsigned short* src = (r < 16)
            ? VH + (bh * 4096 + (size_t)(s0 * 8 + r)) * 64 + dh
            : Vsp + ((size_t)(b * 16 + (r - 16))) * 512 + h * 64 + dh;
        U4 u[4];
        #pragma unroll
        for (int g = 0; g < 4; ++g) u[g].v = ((const uint4*)src)[g];
        unsigned short* dst = &Vt[h][0];
        #pragma unroll
        for (int g = 0; g < 4; ++g)
            #pragma unroll
            for (int ii = 0; ii < 8; ++ii)
                dst[(dh + g * 8 + ii) * 40 + r] = u[g].u[ii];
    }

    // ---- Q / K fragments straight from global ----
    const unsigned short* qp = Qt + (tok0 + l16) * 512 + h * 64 + quad * 8;
    bf16x8 qf0 = *(const bf16x8*)qp;
    bf16x8 qf1 = *(const bf16x8*)(qp + 32);
    const unsigned short* kpt = KH + (bh * 4096 + (size_t)(s0 * 8 + l16)) * 64 + quad * 8;
    bf16x8 kt0 = *(const bf16x8*)kpt;
    bf16x8 kt1 = *(const bf16x8*)(kpt + 32);
    const unsigned short* kps = Ksp + ((size_t)(b * 16 + l16)) * 512 + h * 64 + quad * 8;
    bf16x8 ks0 = *(const bf16x8*)kps;
    bf16x8 ks1 = *(const bf16x8*)(kps + 32);

    // ---- scores ----
    f32x4 sc0 = (f32x4){0.f, 0.f, 0.f, 0.f};
    f32x4 sc1 = (f32x4){0.f, 0.f, 0.f, 0.f};
    sc0 = __builtin_amdgcn_mfma_f32_16x16x32_bf16(qf0, kt0, sc0, 0, 0, 0);
    sc0 = __builtin_amdgcn_mfma_f32_16x16x32_bf16(qf1, kt1, sc0, 0, 0, 0);
    sc1 = __builtin_amdgcn_mfma_f32_16x16x32_bf16(qf0, ks0, sc1, 0, 0, 0);
    sc1 = __builtin_amdgcn_mfma_f32_16x16x32_bf16(qf1, ks1, sc1, 0, 0, 0);

    float madd0 = mask_t[tok0 + l16] ? 0.f : -1e30f;
    bool v0 = ((quad < 2) == (l16 < 8));
    if (!v0) madd0 = -1e30f;
    float madd1 = mask_s[b * 16 + l16] ? 0.f : -1e30f;

    // ---- softmax per row ----
    float w0[4], w1[4];
    #pragma unroll
    for (int i = 0; i < 4; ++i) {
        float a = sc0[i] * 0.125f + madd0;
        float c = sc1[i] * 0.125f + madd1;
        float mx = fmaxf(a, c);
        mx = fmaxf(mx, __shfl_xor(mx, 1));
        mx = fmaxf(mx, __shfl_xor(mx, 2));
        mx = fmaxf(mx, __shfl_xor(mx, 4));
        mx = fmaxf(mx, __shfl_xor(mx, 8));
        float e0 = __expf(a - mx), e1 = __expf(c - mx);
        float se = e0 + e1;
        se += __shfl_xor(se, 1);
        se += __shfl_xor(se, 2);
        se += __shfl_xor(se, 4);
        se += __shfl_xor(se, 8);
        float inv = 1.f / se;
        w0[i] = e0 * inv;
        w1[i] = e1 * inv;
    }

    // ---- write w_t + stage P ----
    int row0 = quad * 4;
    #pragma unroll
    for (int i = 0; i < 4; ++i) {
        int row = row0 + i;
        Pl[h][row * 40 + l16] = f2b(w0[i]);
        Pl[h][row * 40 + 16 + l16] = f2b(w1[i]);
        int s = s0 + (row >> 3), m = row & 7;
        size_t wb = ((((size_t)b * 8 + h) * 512 + s) * 8 + m) * 24;
        if (v0) w_t_out[wb + (l16 & 7)] = w0[i];
        w_t_out[wb + 8 + l16] = w1[i];
    }

    // ---- PV ----
    bf16x8 pa = *(const bf16x8*)&Pl[h][l16 * 40 + quad * 8];
    f32x4 oacc[4];
    #pragma unroll
    for (int j = 0; j < 4; ++j) {
        bf16x8 vb = *(const bf16x8*)&Vt[h][(j * 16 + l16) * 40 + quad * 8];
        oacc[j] = (f32x4){0.f, 0.f, 0.f, 0.f};
        oacc[j] = __builtin_amdgcn_mfma_f32_16x16x32_bf16(pa, vb, oacc[j], 0, 0, 0);
    }
    #pragma unroll
    for (int j = 0; j < 4; ++j)
        #pragma unroll
        for (int ii = 0; ii < 4; ++ii) {
            int row = quad * 4 + ii;
            qkv_t[(tok0 + row) * 512 + h * 64 + j * 16 + l16] = f2b(oacc[j][ii]);
        }
}

// ---------- static attention S1: fused scores + exp + PV, chunked ----------
__global__ __launch_bounds__(256) void static_attn_s1(
    const unsigned short* __restrict__ Qsp, const unsigned short* __restrict__ KH,
    const unsigned short* __restrict__ VH, const unsigned short* __restrict__ Ksp,
    const unsigned short* __restrict__ Vsp,
    const int* __restrict__ mask_t, const int* __restrict__ mask_s,
    float* __restrict__ w_s, float* __restrict__ Ppart, float* __restrict__ Lpart)
{
    int blk = blockIdx.x;
    int bh = blk & 63, c = blk >> 6;
    int b = bh >> 3, h = bh & 7;
    __shared__ __align__(16) unsigned short Klds[32 * 72];
    __shared__ __align__(16) unsigned short Vlds[64 * 40];
    __shared__ __align__(16) unsigned short Plds[16 * 40];
    __shared__ float maskv[32];
    __shared__ float sL[2][16];
    int t = threadIdx.x, wave = t >> 6, lane = t & 63, quad = lane >> 4, l16 = lane & 15;

    bf16x8 qf0 = *(const bf16x8*)(Qsp + ((size_t)(b * 16 + l16)) * 512 + h * 64 + quad * 8);
    bf16x8 qf1 = *(const bf16x8*)(Qsp + ((size_t)(b * 16 + l16)) * 512 + h * 64 + 32 + quad * 8);

    f32x4 pacc = (f32x4){0.f, 0.f, 0.f, 0.f};
    float Lacc[4] = {0.f, 0.f, 0.f, 0.f};
    int d0 = wave * 16;
    int sub = wave >> 1;
    int sr = t >> 3, spart = t & 7;
    int s0 = c * 16, s1 = (c == 7) ? 129 : (s0 + 16);

    for (int st = s0; st < s1; ++st) {
        int key0 = st * 32;
        int kk = key0 + sr;
        uint4 kv = {0, 0, 0, 0}, vv = {0, 0, 0, 0};
        if (kk < 4096) {
            kv = *(const uint4*)(KH + (((size_t)bh) * 4096 + kk) * 64 + spart * 8);
            vv = *(const uint4*)(VH + (((size_t)bh) * 4096 + kk) * 64 + spart * 8);
        } else if (kk < 4112) {
            kv = *(const uint4*)(Ksp + ((size_t)(b * 16 + kk - 4096)) * 512 + h * 64 + spart * 8);
            vv = *(const uint4*)(Vsp + ((size_t)(b * 16 + kk - 4096)) * 512 + h * 64 + spart * 8);
        }
        __syncthreads();
        *(uint4*)&Klds[sr * 72 + spart * 8] = kv;
        {
            U4 u; u.v = vv;
            #pragma unroll
            for (int ii = 0; ii < 8; ++ii) Vlds[(spart * 8 + ii) * 40 + sr] = u.u[ii];
        }
        if (t < 32) {
            int k2 = key0 + t;
            float ma = -1e30f;
            if (k2 < 4096) ma = mask_t[b * 4096 + k2] ? 0.f : -1e30f;
            else if (k2 < 4112) ma = mask_s[b * 16 + k2 - 4096] ? 0.f : -1e30f;
            maskv[t] = ma;
        }
        __syncthreads();
        if ((wave & 1) == 0) {
            bf16x8 kf0 = *(const bf16x8*)&Klds[(sub * 16 + l16) * 72 + quad * 8];
            bf16x8 kf1 = *(const bf16x8*)&Klds[(sub * 16 + l16) * 72 + 32 + quad * 8];
            f32x4 sc = (f32x4){0.f, 0.f, 0.f, 0.f};
            sc = __builtin_amdgcn_mfma_f32_16x16x32_bf16(qf0, kf0, sc, 0, 0, 0);
            sc = __builtin_amdgcn_mfma_f32_16x16x32_bf16(qf1, kf1, sc, 0, 0, 0);
            float ma = maskv[sub * 16 + l16];
            size_t wbase = (((size_t)bh) * 16 + quad * 4) * 4112 + key0 + sub * 16 + l16;
            #pragma unroll
            for (int i = 0; i < 4; ++i) {
                float sv = sc[i] * 0.125f + ma;
                float w = __expf(sv);
                Lacc[i] += w;
                w_s[wbase + (size_t)i * 4112] = w;
                Plds[(quad * 4 + i) * 40 + sub * 16 + l16] = f2b(w);
            }
        }
        __syncthreads();
        bf16x8 pf = *(const bf16x8*)&Plds[l16 * 40 + quad * 8];
        bf16x8 vf = *(const bf16x8*)&Vlds[(d0 + l16) * 40 + quad * 8];
        pacc = __builtin_amdgcn_mfma_f32_16x16x32_bf16(pf, vf, pacc, 0, 0, 0);
    }

    if ((wave & 1) == 0) {
        #pragma unroll
        for (int i = 0; i < 4; ++i) {
            float v = Lacc[i];
            v += __shfl_xor(v, 1);
            v += __shfl_xor(v, 2);
            v += __shfl_xor(v, 4);
            v += __shfl_xor(v, 8);
            Lacc[i] = v;
        }
        if (l16 == 0) {
            #pragma unroll
            for (int i = 0; i < 4; ++i) sL[wave >> 1][quad * 4 + i] = Lacc[i];
        }
    }
    size_t pbase = ((size_t)(bh * 8 + c) * 16 + quad * 4) * 64 + d0 + l16;
    #pragma unroll
    for (int i = 0; i < 4; ++i) Ppart[pbase + (size_t)i * 64] = pacc[i];
    __syncthreads();
    if (t < 16) Lpart[(bh * 8 + c) * 16 + t] = sL[0][t] + sL[1][t];
}

// ---------- static attention S4: combine chunk partials + normalize ----------
__global__ __launch_bounds__(256) void static_attn_s4(
    const float* __restrict__ Ppart, const float* __restrict__ Lpart,
    float* __restrict__ w_s, unsigned short* __restrict__ qkvS)
{
    int bh = blockIdx.x, b = bh >> 3, h = bh & 7;
    __shared__ float invL[16];
    int t = threadIdx.x;
    if (t < 16) {
        float L = 0.f;
        #pragma unroll
        for (int cc = 0; cc < 8; ++cc) L += Lpart[(bh * 8 + cc) * 16 + t];
        invL[t] = 1.f / L;
    }
    __syncthreads();
    #pragma unroll
    for (int i = 0; i < 4; ++i) {
        int idx = t + i * 256;
        int q = idx >> 6, d = idx & 63;
        float s = 0.f;
        #pragma unroll
        for (int cc = 0; cc < 8; ++cc) s += Ppart[((size_t)(bh * 8 + cc) * 16 + q) * 64 + d];
        qkvS[((size_t)(b * 16 + q)) * 512 + h * 64 + d] = f2b(s * invL[q]);
    }
    size_t base = (size_t)bh * 16 * 4112;
    for (int q = 0; q < 16; ++q) {
        float il = invL[q];
        for (int kk = t; kk < 4112; kk += 256) w_s[base + q * 4112 + kk] *= il;
    }
}

// ---------- launch ----------
extern "C" void kernel_launch(void* const* d_in, const int* in_sizes, int n_in,
                              void* d_out, int out_size, void* d_ws, size_t ws_size,
                              hipStream_t stream)
{
    const float* q_t = (const float*)d_in[0];
    const float* k_t = (const float*)d_in[1];
    const float* v_t = (const float*)d_in[2];
    const float* q_s = (const float*)d_in[3];
    const float* k_s = (const float*)d_in[4];
    const float* v_s = (const float*)d_in[5];
    const int* m_t = (const int*)d_in[6];
    const int* m_s = (const int*)d_in[7];
    const float* Wq = (const float*)d_in[8];
    const float* bq = (const float*)d_in[9];
    const float* Wk = (const float*)d_in[10];
    const float* bk = (const float*)d_in[11];
    const float* Wv = (const float*)d_in[12];
    const float* bv = (const float*)d_in[13];
    const float* Wo = (const float*)d_in[14];
    const float* bo = (const float*)d_in[15];

    char* ws = (char*)d_ws;
    size_t off = 0;
    auto alloc = [&](size_t bytes) {
        void* p = ws + off;
        off += (bytes + 255) & ~(size_t)255;
        return p;
    };
    const size_t WB = (size_t)512 * 512 * 2;     // bf16 512x512
    const size_t TB = (size_t)32768 * 512 * 2;   // bf16 32768x512
    const size_t SB = (size_t)128 * 512 * 2;     // bf16 128x512
    unsigned short* WqT = (unsigned short*)alloc(WB);
    unsigned short* WkT = (unsigned short*)alloc(WB);
    unsigned short* WvT = (unsigned short*)alloc(WB);
    unsigned short* WoT = (unsigned short*)alloc(WB);
    unsigned short* Qt   = (unsigned short*)alloc(TB);  // token-major
    unsigned short* KH   = (unsigned short*)alloc(TB);  // head-major [b][h][n][d]
    unsigned short* VH   = (unsigned short*)alloc(TB);  // head-major
    unsigned short* qkvT = (unsigned short*)alloc(TB);  // token-major
    unsigned short* Qsp  = (unsigned short*)alloc(SB);
    unsigned short* Ksp  = (unsigned short*)alloc(SB);
    unsigned short* Vsp  = (unsigned short*)alloc(SB);
    unsigned short* qkvS = (unsigned short*)alloc(SB);
    float* Ppart = (float*)alloc((size_t)64 * 8 * 16 * 64 * 4);  // [bh][chunk][q][d]
    float* Lpart = (float*)alloc((size_t)64 * 8 * 16 * 4);       // [bh][chunk][q]

    float* out    = (float*)d_out;
    float* out_tp = out;                       // [8,512,8,512]
    float* w_t_o  = out + 16777216;            // [8,8,512,8,24]
    float* out_sp = out + 23068672;            // [8,16,512]
    float* w_s_o  = out + 23134208;            // [8,8,16,4112]

    transpose512cvt4<<<dim3(16, 16, 4), 256, 0, stream>>>(Wq, Wk, Wv, Wo, WqT, WkT, WvT, WoT);

    GemmSet gq  = { q_t,  WqT, bq, Qt,   1 };
    GemmSet gk  = { k_t,  WkT, bk, KH,   2 };
    GemmSet gv  = { v_t,  WvT, bv, VH,   2 };
    GemmSet gqs = { q_s,  WqT, bq, Qsp,  1 };
    GemmSet gks = { k_s,  WkT, bk, Ksp,  1 };
    GemmSet gvs = { v_s,  WvT, bv, Vsp,  1 };
    GemmSet got = { qkvT, WoT, bo, out_tp, 0 };
    GemmSet gos = { qkvS, WoT, bo, out_sp, 0 };

    // big QKV: 3 gemms x 64 m-groups x 4 n-panels = 768 blocks
    gemm_bp<true><<<dim3(768), 512, 0, stream>>>(gq, gk, gv, 32768, 64);
    // small QKV: 3 x 1 x 4 = 12 blocks
    gemm_bp<true><<<dim3(12), 512, 0, stream>>>(gqs, gks, gvs, 128, 1);

    temporal_attn<<<2048, 512, 0, stream>>>(Qt, KH, VH, Ksp, Vsp, m_t, m_s, w_t_o, qkvT);
    static_attn_s1<<<512, 256, 0, stream>>>(Qsp, KH, VH, Ksp, Vsp, m_t, m_s, w_s_o, Ppart, Lpart);
    static_attn_s4<<<64, 256, 0, stream>>>(Ppart, Lpart, w_s_o, qkvS);

    // output projections
    gemm_bp<false><<<dim3(256), 512, 0, stream>>>(got, got, got, 32768, 64);
    gemm_bp<false><<<dim3(4), 512, 0, stream>>>(gos, gos, gos, 128, 1);
}

// Round 5
// 550.614 us; speedup vs baseline: 1.0582x; 1.0582x over previous
//
#include <hip/hip_runtime.h>
#include <hip/hip_bf16.h>

// ---------- helpers ----------
typedef __attribute__((ext_vector_type(8))) __bf16 bf16x8;
typedef __attribute__((ext_vector_type(4))) float f32x4;

__device__ __forceinline__ float b2f(unsigned short u) {
    unsigned int x = ((unsigned int)u) << 16;
    float f;
    __builtin_memcpy(&f, &x, 4);
    return f;
}
__device__ __forceinline__ unsigned short f2b(float f) {
    __hip_bfloat16 h = __float2bfloat16(f);
    unsigned short u;
    __builtin_memcpy(&u, &h, 2);
    return u;
}
union U4 { uint4 v; unsigned short u[8]; };

// async global->LDS, 16B per lane, dest = wave-uniform base + lane*16
__device__ __forceinline__ void gload16(const void* g, void* l) {
    __builtin_amdgcn_global_load_lds(
        (const __attribute__((address_space(1))) unsigned int*)g,
        (__attribute__((address_space(3))) unsigned int*)l, 16, 0, 0);
}

// ---------- 4x fused 512x512 transpose + f32->bf16 convert (W matrices) ----------
__global__ __launch_bounds__(256) void transpose512cvt4(
    const float* __restrict__ i0, const float* __restrict__ i1,
    const float* __restrict__ i2, const float* __restrict__ i3,
    unsigned short* __restrict__ o0, unsigned short* __restrict__ o1,
    unsigned short* __restrict__ o2, unsigned short* __restrict__ o3)
{
    const float* in = i0;
    unsigned short* out = o0;
    if (blockIdx.z == 1) { in = i1; out = o1; }
    else if (blockIdx.z == 2) { in = i2; out = o2; }
    else if (blockIdx.z == 3) { in = i3; out = o3; }
    __shared__ float tile[32][33];
    int tx = threadIdx.x & 31, ty = threadIdx.x >> 5;
    int bx = blockIdx.x, by = blockIdx.y;
    #pragma unroll
    for (int i = 0; i < 32; i += 8)
        tile[ty + i][tx] = in[(size_t)(bx * 32 + ty + i) * 512 + by * 32 + tx];
    __syncthreads();
    #pragma unroll
    for (int i = 0; i < 32; i += 8)
        out[(size_t)(by * 32 + ty + i) * 512 + bx * 32 + tx] = f2b(tile[tx][ty + i]);
}

// ---------- GEMM v4: m97-structure with global_load_lds ----------
// C[M,512] = A[M,512] @ Bt[512,512]^T + bias.  128x128 tile, 4 waves (2x2),
// double-buffered LDS, ONE barrier per K-step.  A staged RAW (f32 or bf16) via
// global_load_lds width=16 (coalesced, no VGPR round-trip); f32->bf16 cvt done
// at the register read (VALU overlaps MFMA).  Both-sides XOR swizzle:
// pre-swizzled global source + swizzled ds_read, linear DMA dest (rule #21).
// Grid: G x mtiles x 4 n-panels, np-fastest; m204 bijective XCD chunking so
// the 4 blocks sharing an A-tile run on one XCD (A L2 reuse).
// cmode: 0 = f32 token-major, 1 = bf16 token-major, 2 = bf16 head-major.

struct GemmSet {
    const void* A;
    const unsigned short* B;
    const float* bias;
    void* C;
    int cmode;
};

template<bool AF32>
__global__ __launch_bounds__(256, 3) void gemm_lds(
    GemmSet s0, GemmSet s1, GemmSet s2, int M)
{
    const int K = 512, N = 512;
    __shared__ __align__(16) unsigned char AsB[AF32 ? 32768 : 16384]; // 2 bufs
    __shared__ __align__(16) unsigned char BsB[16384];                // 2 bufs

    int NB = gridDim.x, bid = blockIdx.x;
    // m204 bijective XCD chunking: consecutive wid -> same XCD
    int qq = NB >> 3, rr = NB & 7, xcd = bid & 7, idx = bid >> 3;
    int wid = (xcd < rr ? xcd * (qq + 1) : rr * (qq + 1) + (xcd - rr) * qq) + idx;

    int mtiles = M >> 7;
    int np = wid & 3, t2 = wid >> 2;
    int mt = t2 % mtiles, g = t2 / mtiles;
    GemmSet S = (g == 0) ? s0 : ((g == 1) ? s1 : s2);
    int m0 = mt * 128, n0 = np * 128;

    int t = threadIdx.x;
    int w = t >> 6, lane = t & 63, quad = lane >> 4, l16 = lane & 15;
    int wr = w >> 1, wc = w & 1;

    const float* Ap32 = (const float*)S.A;
    const unsigned short* Ap16 = (const unsigned short*)S.A;
    const unsigned short* Bp = S.B;

    f32x4 acc[4][4];
    #pragma unroll
    for (int i = 0; i < 4; ++i)
        #pragma unroll
        for (int j = 0; j < 4; ++j) acc[i][j] = (f32x4){0.f, 0.f, 0.f, 0.f};

    // ---- staging: per K-step tile A[128x32], B[128x32]; linear LDS rows,
    // source granule pre-swizzled so swizzled ds_read returns original data.
    auto STAGE = [&](int buf, int k0) {
        if constexpr (AF32) {
            // A f32: rows of 128 B, granules of 16 B (4 f32), swz = row&7
            #pragma unroll
            for (int s = 0; s < 4; ++s) {
                int r0 = w * 32 + s * 8;
                int row = r0 + (lane >> 3);
                int g2 = (lane & 7) ^ (row & 7);
                gload16(Ap32 + (size_t)(m0 + row) * K + k0 + g2 * 4,
                        AsB + buf * 16384 + r0 * 128);
            }
        } else {
            // A bf16: rows of 64 B, granules of 16 B (8 bf16), swz = (row>>1)&3
            #pragma unroll
            for (int s = 0; s < 2; ++s) {
                int r0 = w * 32 + s * 16;
                int row = r0 + (lane >> 2);
                int g2 = (lane & 3) ^ ((row >> 1) & 3);
                gload16(Ap16 + (size_t)(m0 + row) * K + k0 + g2 * 8,
                        AsB + buf * 8192 + r0 * 64);
            }
        }
        #pragma unroll
        for (int s = 0; s < 2; ++s) {
            int r0 = w * 32 + s * 16;
            int row = r0 + (lane >> 2);
            int g2 = (lane & 3) ^ ((row >> 1) & 3);
            gload16(Bp + (size_t)(n0 + row) * K + k0 + g2 * 8,
                    BsB + buf * 8192 + r0 * 64);
        }
    };

    auto COMPUTE = [&](int buf) {
        bf16x8 af[4], bfj[4];
        #pragma unroll
        for (int j = 0; j < 4; ++j) {
            int r = wc * 64 + j * 16 + l16;
            bfj[j] = *(const bf16x8*)(BsB + buf * 8192 + r * 64
                                      + ((quad ^ ((r >> 1) & 3)) * 16));
        }
        #pragma unroll
        for (int i = 0; i < 4; ++i) {
            int r = wr * 64 + i * 16 + l16;
            if constexpr (AF32) {
                const float4* rowp = (const float4*)(AsB + buf * 16384 + r * 128);
                float4 f0 = rowp[(2 * quad) ^ (r & 7)];
                float4 f1 = rowp[(2 * quad + 1) ^ (r & 7)];
                U4 u;
                u.u[0] = f2b(f0.x); u.u[1] = f2b(f0.y); u.u[2] = f2b(f0.z); u.u[3] = f2b(f0.w);
                u.u[4] = f2b(f1.x); u.u[5] = f2b(f1.y); u.u[6] = f2b(f1.z); u.u[7] = f2b(f1.w);
                af[i] = *(bf16x8*)&u;
            } else {
                af[i] = *(const bf16x8*)(AsB + buf * 8192 + r * 64
                                         + ((quad ^ ((r >> 1) & 3)) * 16));
            }
        }
        #pragma unroll
        for (int i = 0; i < 4; ++i)
            #pragma unroll
            for (int j = 0; j < 4; ++j)
                acc[i][j] = __builtin_amdgcn_mfma_f32_16x16x32_bf16(af[i], bfj[j], acc[i][j], 0, 0, 0);
    };

    STAGE(0, 0);
    __syncthreads();                        // drain DMA, buffer 0 ready
    #pragma unroll 2
    for (int it = 0; it < 16; ++it) {
        int cur = it & 1;
        if (it < 15) STAGE(cur ^ 1, (it + 1) * 32);  // issue-early: compute covers latency
        COMPUTE(cur);
        __syncthreads();                    // vmcnt+lgkm drain + barrier
    }

    // epilogue. C/D layout: col = lane&15, row = quad*4 + reg
    int cmode = S.cmode;
    #pragma unroll
    for (int i = 0; i < 4; ++i) {
        #pragma unroll
        for (int j = 0; j < 4; ++j) {
            int row = m0 + wr * 64 + i * 16 + quad * 4;
            int col = n0 + wc * 64 + j * 16 + l16;
            float bc = S.bias[col];
            #pragma unroll
            for (int ii = 0; ii < 4; ++ii) {
                float v = acc[i][j][ii] + bc;
                int R = row + ii;
                if (cmode == 0) {
                    ((float*)S.C)[(size_t)R * N + col] = v;
                } else if (cmode == 1) {
                    ((unsigned short*)S.C)[(size_t)R * N + col] = f2b(v);
                } else {
                    int bb = R >> 12, n = R & 4095, hh = col >> 6, d = col & 63;
                    ((unsigned short*)S.C)[(((size_t)bb * 8 + hh) * 4096 + n) * 64 + d] = f2b(v);
                }
            }
        }
    }
}

// ---------- temporal attention v2: MFMA, one block per (b, s-pair), 8 waves = 8 heads ----------
__global__ __launch_bounds__(512) void temporal_attn(
    const unsigned short* __restrict__ Qt, const unsigned short* __restrict__ KH,
    const unsigned short* __restrict__ VH, const unsigned short* __restrict__ Ksp,
    const unsigned short* __restrict__ Vsp,
    const int* __restrict__ mask_t, const int* __restrict__ mask_s,
    float* __restrict__ w_t_out, unsigned short* __restrict__ qkv_t)
{
    int blk = blockIdx.x;              // b*256 + sp
    int b = blk >> 8, sp = blk & 255;
    int s0 = sp * 2;
    int t = threadIdx.x;
    int h = t >> 6, lane = t & 63, quad = lane >> 4, l16 = lane & 15;

    __shared__ __align__(16) unsigned short Vt[8][64 * 40];  // per-head V^T [d][key(32)+pad]
    __shared__ __align__(16) unsigned short Pl[8][16 * 40];  // per-head P  [q][key(32)+pad]

    size_t bh = (size_t)(b * 8 + h);
    size_t tok0 = ((size_t)(b * 512 + s0)) * 8;

    // ---- stage V^T (wave-private; keys 0-15 temporal, 16-31 static) ----
    {
        int r = lane & 31, dh = (lane >> 5) * 32;
        const unsigned short* src = (r < 16)
            ? VH + (bh * 4096 + (size_t)(s0 * 8 + r)) * 64 + dh
            : Vsp + ((size_t)(b * 16 + (r - 16))) * 512 + h * 64 + dh;
        U4 u[4];
        #pragma unroll
        for (int g = 0; g < 4; ++g) u[g].v = ((const uint4*)src)[g];
        unsigned short* dst = &Vt[h][0];
        #pragma unroll
        for (int g = 0; g < 4; ++g)
            #pragma unroll
            for (int ii = 0; ii < 8; ++ii)
                dst[(dh + g * 8 + ii) * 40 + r] = u[g].u[ii];
    }

    // ---- Q / K fragments straight from global ----
    const unsigned short* qp = Qt + (tok0 + l16) * 512 + h * 64 + quad * 8;
    bf16x8 qf0 = *(const bf16x8*)qp;
    bf16x8 qf1 = *(const bf16x8*)(qp + 32);
    const unsigned short* kpt = KH + (bh * 4096 + (size_t)(s0 * 8 + l16)) * 64 + quad * 8;
    bf16x8 kt0 = *(const bf16x8*)kpt;
    bf16x8 kt1 = *(const bf16x8*)(kpt + 32);
    const unsigned short* kps = Ksp + ((size_t)(b * 16 + l16)) * 512 + h * 64 + quad * 8;
    bf16x8 ks0 = *(const bf16x8*)kps;
    bf16x8 ks1 = *(const bf16x8*)(kps + 32);

    // ---- scores ----
    f32x4 sc0 = (f32x4){0.f, 0.f, 0.f, 0.f};
    f32x4 sc1 = (f32x4){0.f, 0.f, 0.f, 0.f};
    sc0 = __builtin_amdgcn_mfma_f32_16x16x32_bf16(qf0, kt0, sc0, 0, 0, 0);
    sc0 = __builtin_amdgcn_mfma_f32_16x16x32_bf16(qf1, kt1, sc0, 0, 0, 0);
    sc1 = __builtin_amdgcn_mfma_f32_16x16x32_bf16(qf0, ks0, sc1, 0, 0, 0);
    sc1 = __builtin_amdgcn_mfma_f32_16x16x32_bf16(qf1, ks1, sc1, 0, 0, 0);

    float madd0 = mask_t[tok0 + l16] ? 0.f : -1e30f;
    bool v0 = ((quad < 2) == (l16 < 8));
    if (!v0) madd0 = -1e30f;
    float madd1 = mask_s[b * 16 + l16] ? 0.f : -1e30f;

    // ---- softmax per row ----
    float w0[4], w1[4];
    #pragma unroll
    for (int i = 0; i < 4; ++i) {
        float a = sc0[i] * 0.125f + madd0;
        float c = sc1[i] * 0.125f + madd1;
        float mx = fmaxf(a, c);
        mx = fmaxf(mx, __shfl_xor(mx, 1));
        mx = fmaxf(mx, __shfl_xor(mx, 2));
        mx = fmaxf(mx, __shfl_xor(mx, 4));
        mx = fmaxf(mx, __shfl_xor(mx, 8));
        float e0 = __expf(a - mx), e1 = __expf(c - mx);
        float se = e0 + e1;
        se += __shfl_xor(se, 1);
        se += __shfl_xor(se, 2);
        se += __shfl_xor(se, 4);
        se += __shfl_xor(se, 8);
        float inv = 1.f / se;
        w0[i] = e0 * inv;
        w1[i] = e1 * inv;
    }

    // ---- write w_t + stage P ----
    int row0 = quad * 4;
    #pragma unroll
    for (int i = 0; i < 4; ++i) {
        int row = row0 + i;
        Pl[h][row * 40 + l16] = f2b(w0[i]);
        Pl[h][row * 40 + 16 + l16] = f2b(w1[i]);
        int s = s0 + (row >> 3), m = row & 7;
        size_t wb = ((((size_t)b * 8 + h) * 512 + s) * 8 + m) * 24;
        if (v0) w_t_out[wb + (l16 & 7)] = w0[i];
        w_t_out[wb + 8 + l16] = w1[i];
    }

    // ---- PV ----
    bf16x8 pa = *(const bf16x8*)&Pl[h][l16 * 40 + quad * 8];
    f32x4 oacc[4];
    #pragma unroll
    for (int j = 0; j < 4; ++j) {
        bf16x8 vb = *(const bf16x8*)&Vt[h][(j * 16 + l16) * 40 + quad * 8];
        oacc[j] = (f32x4){0.f, 0.f, 0.f, 0.f};
        oacc[j] = __builtin_amdgcn_mfma_f32_16x16x32_bf16(pa, vb, oacc[j], 0, 0, 0);
    }
    #pragma unroll
    for (int j = 0; j < 4; ++j)
        #pragma unroll
        for (int ii = 0; ii < 4; ++ii) {
            int row = quad * 4 + ii;
            qkv_t[(tok0 + row) * 512 + h * 64 + j * 16 + l16] = f2b(oacc[j][ii]);
        }
}

// ---------- static attention S1: fused scores + exp + PV, chunked ----------
__global__ __launch_bounds__(256) void static_attn_s1(
    const unsigned short* __restrict__ Qsp, const unsigned short* __restrict__ KH,
    const unsigned short* __restrict__ VH, const unsigned short* __restrict__ Ksp,
    const unsigned short* __restrict__ Vsp,
    const int* __restrict__ mask_t, const int* __restrict__ mask_s,
    float* __restrict__ w_s, float* __restrict__ Ppart, float* __restrict__ Lpart)
{
    int blk = blockIdx.x;
    int bh = blk & 63, c = blk >> 6;
    int b = bh >> 3, h = bh & 7;
    __shared__ __align__(16) unsigned short Klds[32 * 72];
    __shared__ __align__(16) unsigned short Vlds[64 * 40];
    __shared__ __align__(16) unsigned short Plds[16 * 40];
    __shared__ float maskv[32];
    __shared__ float sL[2][16];
    int t = threadIdx.x, wave = t >> 6, lane = t & 63, quad = lane >> 4, l16 = lane & 15;

    bf16x8 qf0 = *(const bf16x8*)(Qsp + ((size_t)(b * 16 + l16)) * 512 + h * 64 + quad * 8);
    bf16x8 qf1 = *(const bf16x8*)(Qsp + ((size_t)(b * 16 + l16)) * 512 + h * 64 + 32 + quad * 8);

    f32x4 pacc = (f32x4){0.f, 0.f, 0.f, 0.f};
    float Lacc[4] = {0.f, 0.f, 0.f, 0.f};
    int d0 = wave * 16;
    int sub = wave >> 1;
    int sr = t >> 3, spart = t & 7;
    int s0 = c * 16, s1 = (c == 7) ? 129 : (s0 + 16);

    for (int st = s0; st < s1; ++st) {
        int key0 = st * 32;
        int kk = key0 + sr;
        uint4 kv = {0, 0, 0, 0}, vv = {0, 0, 0, 0};
        if (kk < 4096) {
            kv = *(const uint4*)(KH + (((size_t)bh) * 4096 + kk) * 64 + spart * 8);
            vv = *(const uint4*)(VH + (((size_t)bh) * 4096 + kk) * 64 + spart * 8);
        } else if (kk < 4112) {
            kv = *(const uint4*)(Ksp + ((size_t)(b * 16 + kk - 4096)) * 512 + h * 64 + spart * 8);
            vv = *(const uint4*)(Vsp + ((size_t)(b * 16 + kk - 4096)) * 512 + h * 64 + spart * 8);
        }
        __syncthreads();
        *(uint4*)&Klds[sr * 72 + spart * 8] = kv;
        {
            U4 u; u.v = vv;
            #pragma unroll
            for (int ii = 0; ii < 8; ++ii) Vlds[(spart * 8 + ii) * 40 + sr] = u.u[ii];
        }
        if (t < 32) {
            int k2 = key0 + t;
            float ma = -1e30f;
            if (k2 < 4096) ma = mask_t[b * 4096 + k2] ? 0.f : -1e30f;
            else if (k2 < 4112) ma = mask_s[b * 16 + k2 - 4096] ? 0.f : -1e30f;
            maskv[t] = ma;
        }
        __syncthreads();
        if ((wave & 1) == 0) {
            bf16x8 kf0 = *(const bf16x8*)&Klds[(sub * 16 + l16) * 72 + quad * 8];
            bf16x8 kf1 = *(const bf16x8*)&Klds[(sub * 16 + l16) * 72 + 32 + quad * 8];
            f32x4 sc = (f32x4){0.f, 0.f, 0.f, 0.f};
            sc = __builtin_amdgcn_mfma_f32_16x16x32_bf16(qf0, kf0, sc, 0, 0, 0);
            sc = __builtin_amdgcn_mfma_f32_16x16x32_bf16(qf1, kf1, sc, 0, 0, 0);
            float ma = maskv[sub * 16 + l16];
            size_t wbase = (((size_t)bh) * 16 + quad * 4) * 4112 + key0 + sub * 16 + l16;
            #pragma unroll
            for (int i = 0; i < 4; ++i) {
                float sv = sc[i] * 0.125f + ma;
                float w = __expf(sv);
                Lacc[i] += w;
                w_s[wbase + (size_t)i * 4112] = w;
                Plds[(quad * 4 + i) * 40 + sub * 16 + l16] = f2b(w);
            }
        }
        __syncthreads();
        bf16x8 pf = *(const bf16x8*)&Plds[l16 * 40 + quad * 8];
        bf16x8 vf = *(const bf16x8*)&Vlds[(d0 + l16) * 40 + quad * 8];
        pacc = __builtin_amdgcn_mfma_f32_16x16x32_bf16(pf, vf, pacc, 0, 0, 0);
    }

    if ((wave & 1) == 0) {
        #pragma unroll
        for (int i = 0; i < 4; ++i) {
            float v = Lacc[i];
            v += __shfl_xor(v, 1);
            v += __shfl_xor(v, 2);
            v += __shfl_xor(v, 4);
            v += __shfl_xor(v, 8);
            Lacc[i] = v;
        }
        if (l16 == 0) {
            #pragma unroll
            for (int i = 0; i < 4; ++i) sL[wave >> 1][quad * 4 + i] = Lacc[i];
        }
    }
    size_t pbase = ((size_t)(bh * 8 + c) * 16 + quad * 4) * 64 + d0 + l16;
    #pragma unroll
    for (int i = 0; i < 4; ++i) Ppart[pbase + (size_t)i * 64] = pacc[i];
    __syncthreads();
    if (t < 16) Lpart[(bh * 8 + c) * 16 + t] = sL[0][t] + sL[1][t];
}

// ---------- static attention S4: combine chunk partials + normalize ----------
__global__ __launch_bounds__(256) void static_attn_s4(
    const float* __restrict__ Ppart, const float* __restrict__ Lpart,
    float* __restrict__ w_s, unsigned short* __restrict__ qkvS)
{
    int bh = blockIdx.x, b = bh >> 3, h = bh & 7;
    __shared__ float invL[16];
    int t = threadIdx.x;
    if (t < 16) {
        float L = 0.f;
        #pragma unroll
        for (int cc = 0; cc < 8; ++cc) L += Lpart[(bh * 8 + cc) * 16 + t];
        invL[t] = 1.f / L;
    }
    __syncthreads();
    #pragma unroll
    for (int i = 0; i < 4; ++i) {
        int idx = t + i * 256;
        int q = idx >> 6, d = idx & 63;
        float s = 0.f;
        #pragma unroll
        for (int cc = 0; cc < 8; ++cc) s += Ppart[((size_t)(bh * 8 + cc) * 16 + q) * 64 + d];
        qkvS[((size_t)(b * 16 + q)) * 512 + h * 64 + d] = f2b(s * invL[q]);
    }
    size_t base = (size_t)bh * 16 * 4112;
    for (int q = 0; q < 16; ++q) {
        float il = invL[q];
        for (int kk = t; kk < 4112; kk += 256) w_s[base + q * 4112 + kk] *= il;
    }
}

// ---------- launch ----------
extern "C" void kernel_launch(void* const* d_in, const int* in_sizes, int n_in,
                              void* d_out, int out_size, void* d_ws, size_t ws_size,
                              hipStream_t stream)
{
    const float* q_t = (const float*)d_in[0];
    const float* k_t = (const float*)d_in[1];
    const float* v_t = (const float*)d_in[2];
    const float* q_s = (const float*)d_in[3];
    const float* k_s = (const float*)d_in[4];
    const float* v_s = (const float*)d_in[5];
    const int* m_t = (const int*)d_in[6];
    const int* m_s = (const int*)d_in[7];
    const float* Wq = (const float*)d_in[8];
    const float* bq = (const float*)d_in[9];
    const float* Wk = (const float*)d_in[10];
    const float* bk = (const float*)d_in[11];
    const float* Wv = (const float*)d_in[12];
    const float* bv = (const float*)d_in[13];
    const float* Wo = (const float*)d_in[14];
    const float* bo = (const float*)d_in[15];

    char* ws = (char*)d_ws;
    size_t off = 0;
    auto alloc = [&](size_t bytes) {
        void* p = ws + off;
        off += (bytes + 255) & ~(size_t)255;
        return p;
    };
    const size_t WB = (size_t)512 * 512 * 2;     // bf16 512x512
    const size_t TB = (size_t)32768 * 512 * 2;   // bf16 32768x512
    const size_t SB = (size_t)128 * 512 * 2;     // bf16 128x512
    unsigned short* WqT = (unsigned short*)alloc(WB);
    unsigned short* WkT = (unsigned short*)alloc(WB);
    unsigned short* WvT = (unsigned short*)alloc(WB);
    unsigned short* WoT = (unsigned short*)alloc(WB);
    unsigned short* Qt   = (unsigned short*)alloc(TB);  // token-major
    unsigned short* KH   = (unsigned short*)alloc(TB);  // head-major [b][h][n][d]
    unsigned short* VH   = (unsigned short*)alloc(TB);  // head-major
    unsigned short* qkvT = (unsigned short*)alloc(TB);  // token-major
    unsigned short* Qsp  = (unsigned short*)alloc(SB);
    unsigned short* Ksp  = (unsigned short*)alloc(SB);
    unsigned short* Vsp  = (unsigned short*)alloc(SB);
    unsigned short* qkvS = (unsigned short*)alloc(SB);
    float* Ppart = (float*)alloc((size_t)64 * 8 * 16 * 64 * 4);  // [bh][chunk][q][d]
    float* Lpart = (float*)alloc((size_t)64 * 8 * 16 * 4);       // [bh][chunk][q]

    float* out    = (float*)d_out;
    float* out_tp = out;                       // [8,512,8,512]
    float* w_t_o  = out + 16777216;            // [8,8,512,8,24]
    float* out_sp = out + 23068672;            // [8,16,512]
    float* w_s_o  = out + 23134208;            // [8,8,16,4112]

    transpose512cvt4<<<dim3(16, 16, 4), 256, 0, stream>>>(Wq, Wk, Wv, Wo, WqT, WkT, WvT, WoT);

    GemmSet gq  = { q_t,  WqT, bq, Qt,   1 };
    GemmSet gk  = { k_t,  WkT, bk, KH,   2 };
    GemmSet gv  = { v_t,  WvT, bv, VH,   2 };
    GemmSet gqs = { q_s,  WqT, bq, Qsp,  1 };
    GemmSet gks = { k_s,  WkT, bk, Ksp,  1 };
    GemmSet gvs = { v_s,  WvT, bv, Vsp,  1 };
    GemmSet got = { qkvT, WoT, bo, out_tp, 0 };
    GemmSet gos = { qkvS, WoT, bo, out_sp, 0 };

    // big QKV: 3 gemms x 256 m-tiles x 4 n-panels = 3072 blocks
    gemm_lds<true><<<dim3(3072), 256, 0, stream>>>(gq, gk, gv, 32768);
    // small QKV: 3 x 1 x 4 = 12 blocks
    gemm_lds<true><<<dim3(12), 256, 0, stream>>>(gqs, gks, gvs, 128);

    temporal_attn<<<2048, 512, 0, stream>>>(Qt, KH, VH, Ksp, Vsp, m_t, m_s, w_t_o, qkvT);
    static_attn_s1<<<512, 256, 0, stream>>>(Qsp, KH, VH, Ksp, Vsp, m_t, m_s, w_s_o, Ppart, Lpart);
    static_attn_s4<<<64, 256, 0, stream>>>(Ppart, Lpart, w_s_o, qkvS);

    // output projections
    gemm_lds<false><<<dim3(1024), 256, 0, stream>>>(got, got, got, 32768);
    gemm_lds<false><<<dim3(4), 256, 0, stream>>>(gos, gos, gos, 128);
}

// Round 6
// 544.822 us; speedup vs baseline: 1.0695x; 1.0106x over previous
//
#include <hip/hip_runtime.h>
#include <hip/hip_bf16.h>

// ---------- helpers ----------
typedef __attribute__((ext_vector_type(8))) __bf16 bf16x8;
typedef __attribute__((ext_vector_type(4))) float f32x4;

__device__ __forceinline__ float b2f(unsigned short u) {
    unsigned int x = ((unsigned int)u) << 16;
    float f;
    __builtin_memcpy(&f, &x, 4);
    return f;
}
__device__ __forceinline__ unsigned short f2b(float f) {
    __hip_bfloat16 h = __float2bfloat16(f);
    unsigned short u;
    __builtin_memcpy(&u, &h, 2);
    return u;
}
union U4 { uint4 v; unsigned short u[8]; };

// async global->LDS, 16B per lane, dest = wave-uniform base + lane*16
__device__ __forceinline__ void gload16(const void* g, void* l) {
    __builtin_amdgcn_global_load_lds(
        (const __attribute__((address_space(1))) unsigned int*)g,
        (__attribute__((address_space(3))) unsigned int*)l, 16, 0, 0);
}

// ---------- bulk f32 -> bf16 convert: 3 big (16.7M) + 3 small (64K) arrays ----------
__global__ __launch_bounds__(256) void cvt6(
    const float* __restrict__ a0, const float* __restrict__ a1, const float* __restrict__ a2,
    const float* __restrict__ a3, const float* __restrict__ a4, const float* __restrict__ a5,
    unsigned short* __restrict__ d0, unsigned short* __restrict__ d1, unsigned short* __restrict__ d2,
    unsigned short* __restrict__ d3, unsigned short* __restrict__ d4, unsigned short* __restrict__ d5)
{
    const size_t BIG = 16777216, SMALL = 65536;
    const size_t TOTV = (3 * BIG + 3 * SMALL) / 8;
    for (size_t v = (size_t)blockIdx.x * 256 + threadIdx.x; v < TOTV;
         v += (size_t)gridDim.x * 256) {
        size_t e = v * 8;
        const float* src;
        unsigned short* dst;
        size_t off;
        if (e < 3 * BIG) {
            size_t g = e >> 24;                 // /BIG
            off = e - g * BIG;
            src = g == 0 ? a0 : (g == 1 ? a1 : a2);
            dst = g == 0 ? d0 : (g == 1 ? d1 : d2);
        } else {
            size_t e2 = e - 3 * BIG;
            size_t g = e2 >> 16;                // /SMALL
            off = e2 - g * SMALL;
            src = g == 0 ? a3 : (g == 1 ? a4 : a5);
            dst = g == 0 ? d3 : (g == 1 ? d4 : d5);
        }
        float4 f0 = *(const float4*)(src + off);
        float4 f1 = *(const float4*)(src + off + 4);
        U4 u;
        u.u[0] = f2b(f0.x); u.u[1] = f2b(f0.y); u.u[2] = f2b(f0.z); u.u[3] = f2b(f0.w);
        u.u[4] = f2b(f1.x); u.u[5] = f2b(f1.y); u.u[6] = f2b(f1.z); u.u[7] = f2b(f1.w);
        *(uint4*)(dst + off) = u.v;
    }
}

// ---------- 4x fused 512x512 transpose + f32->bf16 convert (W matrices) ----------
__global__ __launch_bounds__(256) void transpose512cvt4(
    const float* __restrict__ i0, const float* __restrict__ i1,
    const float* __restrict__ i2, const float* __restrict__ i3,
    unsigned short* __restrict__ o0, unsigned short* __restrict__ o1,
    unsigned short* __restrict__ o2, unsigned short* __restrict__ o3)
{
    const float* in = i0;
    unsigned short* out = o0;
    if (blockIdx.z == 1) { in = i1; out = o1; }
    else if (blockIdx.z == 2) { in = i2; out = o2; }
    else if (blockIdx.z == 3) { in = i3; out = o3; }
    __shared__ float tile[32][33];
    int tx = threadIdx.x & 31, ty = threadIdx.x >> 5;
    int bx = blockIdx.x, by = blockIdx.y;
    #pragma unroll
    for (int i = 0; i < 32; i += 8)
        tile[ty + i][tx] = in[(size_t)(bx * 32 + ty + i) * 512 + by * 32 + tx];
    __syncthreads();
    #pragma unroll
    for (int i = 0; i < 32; i += 8)
        out[(size_t)(by * 32 + ty + i) * 512 + bx * 32 + tx] = f2b(tile[tx][ty + i]);
}

// ---------- GEMM v5: pure-bf16 m97 loop ----------
// C[M,512] = A[M,512] @ Bt[512,512]^T + bias, all operands bf16.
// 128x128 tile, 4 waves (2x2), double-buffered LDS (32 KB), 1 barrier/K-step.
// Staging via global_load_lds w=16 (linear dest) with pre-swizzled source;
// swizzled ds_read_b128 -> conflict-free.  No cvt in the loop: 8 ds_read +
// 4 gload + 16 MFMA per wave per step.  m204 bijective XCD chunking, np-fastest.
// cmode: 0 = f32 token-major, 1 = bf16 token-major, 2 = bf16 head-major.

struct GemmSet {
    const unsigned short* A;
    const unsigned short* B;
    const float* bias;
    void* C;
    int cmode;
};

__global__ __launch_bounds__(256, 4) void gemm_bf(
    GemmSet s0, GemmSet s1, GemmSet s2, int M)
{
    const int K = 512, N = 512;
    __shared__ __align__(16) unsigned char AsB[16384]; // 2 bufs x 8 KB
    __shared__ __align__(16) unsigned char BsB[16384];

    int NB = gridDim.x, bid = blockIdx.x;
    int qq = NB >> 3, rr = NB & 7, xcd = bid & 7, idx = bid >> 3;
    int wid = (xcd < rr ? xcd * (qq + 1) : rr * (qq + 1) + (xcd - rr) * qq) + idx;

    int mtiles = M >> 7;
    int np = wid & 3, t2 = wid >> 2;
    int mt = t2 % mtiles, g = t2 / mtiles;
    GemmSet S = (g == 0) ? s0 : ((g == 1) ? s1 : s2);
    int m0 = mt * 128, n0 = np * 128;

    int t = threadIdx.x;
    int w = t >> 6, lane = t & 63, quad = lane >> 4, l16 = lane & 15;
    int wr = w >> 1, wc = w & 1;

    const unsigned short* Ap = S.A;
    const unsigned short* Bp = S.B;

    f32x4 acc[4][4];
    #pragma unroll
    for (int i = 0; i < 4; ++i)
        #pragma unroll
        for (int j = 0; j < 4; ++j) acc[i][j] = (f32x4){0.f, 0.f, 0.f, 0.f};

    // staging: rows of 64 B (32 bf16), granules of 16 B, swz = (row>>1)&3
    auto STAGE = [&](int buf, int k0) {
        #pragma unroll
        for (int s = 0; s < 2; ++s) {
            int r0 = w * 32 + s * 16;
            int row = r0 + (lane >> 2);
            int g2 = (lane & 3) ^ ((row >> 1) & 3);
            gload16(Ap + (size_t)(m0 + row) * K + k0 + g2 * 8,
                    AsB + buf * 8192 + r0 * 64);
        }
        #pragma unroll
        for (int s = 0; s < 2; ++s) {
            int r0 = w * 32 + s * 16;
            int row = r0 + (lane >> 2);
            int g2 = (lane & 3) ^ ((row >> 1) & 3);
            gload16(Bp + (size_t)(n0 + row) * K + k0 + g2 * 8,
                    BsB + buf * 8192 + r0 * 64);
        }
    };

    auto COMPUTE = [&](int buf) {
        bf16x8 af[4], bfj[4];
        #pragma unroll
        for (int j = 0; j < 4; ++j) {
            int r = wc * 64 + j * 16 + l16;
            bfj[j] = *(const bf16x8*)(BsB + buf * 8192 + r * 64
                                      + ((quad ^ ((r >> 1) & 3)) * 16));
        }
        #pragma unroll
        for (int i = 0; i < 4; ++i) {
            int r = wr * 64 + i * 16 + l16;
            af[i] = *(const bf16x8*)(AsB + buf * 8192 + r * 64
                                     + ((quad ^ ((r >> 1) & 3)) * 16));
        }
        #pragma unroll
        for (int i = 0; i < 4; ++i)
            #pragma unroll
            for (int j = 0; j < 4; ++j)
                acc[i][j] = __builtin_amdgcn_mfma_f32_16x16x32_bf16(af[i], bfj[j], acc[i][j], 0, 0, 0);
    };

    STAGE(0, 0);
    __syncthreads();                        // drain DMA, buffer 0 ready
    #pragma unroll 2
    for (int it = 0; it < 16; ++it) {
        int cur = it & 1;
        if (it < 15) STAGE(cur ^ 1, (it + 1) * 32);  // issue-early: MFMA covers latency
        COMPUTE(cur);
        __syncthreads();
    }

    // epilogue. C/D layout: col = lane&15, row = quad*4 + reg
    int cmode = S.cmode;
    #pragma unroll
    for (int i = 0; i < 4; ++i) {
        #pragma unroll
        for (int j = 0; j < 4; ++j) {
            int row = m0 + wr * 64 + i * 16 + quad * 4;
            int col = n0 + wc * 64 + j * 16 + l16;
            float bc = S.bias[col];
            #pragma unroll
            for (int ii = 0; ii < 4; ++ii) {
                float v = acc[i][j][ii] + bc;
                int R = row + ii;
                if (cmode == 0) {
                    ((float*)S.C)[(size_t)R * N + col] = v;
                } else if (cmode == 1) {
                    ((unsigned short*)S.C)[(size_t)R * N + col] = f2b(v);
                } else {
                    int bb = R >> 12, n = R & 4095, hh = col >> 6, d = col & 63;
                    ((unsigned short*)S.C)[(((size_t)bb * 8 + hh) * 4096 + n) * 64 + d] = f2b(v);
                }
            }
        }
    }
}

// ---------- temporal attention v2: MFMA, one block per (b, s-pair), 8 waves = 8 heads ----------
__global__ __launch_bounds__(512) void temporal_attn(
    const unsigned short* __restrict__ Qt, const unsigned short* __restrict__ KH,
    const unsigned short* __restrict__ VH, const unsigned short* __restrict__ Ksp,
    const unsigned short* __restrict__ Vsp,
    const int* __restrict__ mask_t, const int* __restrict__ mask_s,
    float* __restrict__ w_t_out, unsigned short* __restrict__ qkv_t)
{
    int blk = blockIdx.x;              // b*256 + sp
    int b = blk >> 8, sp = blk & 255;
    int s0 = sp * 2;
    int t = threadIdx.x;
    int h = t >> 6, lane = t & 63, quad = lane >> 4, l16 = lane & 15;

    __shared__ __align__(16) unsigned short Vt[8][64 * 40];  // per-head V^T [d][key(32)+pad]
    __shared__ __align__(16) unsigned short Pl[8][16 * 40];  // per-head P  [q][key(32)+pad]

    size_t bh = (size_t)(b * 8 + h);
    size_t tok0 = ((size_t)(b * 512 + s0)) * 8;

    // ---- stage V^T (wave-private; keys 0-15 temporal, 16-31 static) ----
    {
        int r = lane & 31, dh = (lane >> 5) * 32;
        const unsigned short* src = (r < 16)
            ? VH + (bh * 4096 + (size_t)(s0 * 8 + r)) * 64 + dh
            : Vsp + ((size_t)(b * 16 + (r - 16))) * 512 + h * 64 + dh;
        U4 u[4];
        #pragma unroll
        for (int g = 0; g < 4; ++g) u[g].v = ((const uint4*)src)[g];
        unsigned short* dst = &Vt[h][0];
        #pragma unroll
        for (int g = 0; g < 4; ++g)
            #pragma unroll
            for (int ii = 0; ii < 8; ++ii)
                dst[(dh + g * 8 + ii) * 40 + r] = u[g].u[ii];
    }

    // ---- Q / K fragments straight from global ----
    const unsigned short* qp = Qt + (tok0 + l16) * 512 + h * 64 + quad * 8;
    bf16x8 qf0 = *(const bf16x8*)qp;
    bf16x8 qf1 = *(const bf16x8*)(qp + 32);
    const unsigned short* kpt = KH + (bh * 4096 + (size_t)(s0 * 8 + l16)) * 64 + quad * 8;
    bf16x8 kt0 = *(const bf16x8*)kpt;
    bf16x8 kt1 = *(const bf16x8*)(kpt + 32);
    const unsigned short* kps = Ksp + ((size_t)(b * 16 + l16)) * 512 + h * 64 + quad * 8;
    bf16x8 ks0 = *(const bf16x8*)kps;
    bf16x8 ks1 = *(const bf16x8*)(kps + 32);

    // ---- scores ----
    f32x4 sc0 = (f32x4){0.f, 0.f, 0.f, 0.f};
    f32x4 sc1 = (f32x4){0.f, 0.f, 0.f, 0.f};
    sc0 = __builtin_amdgcn_mfma_f32_16x16x32_bf16(qf0, kt0, sc0, 0, 0, 0);
    sc0 = __builtin_amdgcn_mfma_f32_16x16x32_bf16(qf1, kt1, sc0, 0, 0, 0);
    sc1 = __builtin_amdgcn_mfma_f32_16x16x32_bf16(qf0, ks0, sc1, 0, 0, 0);
    sc1 = __builtin_amdgcn_mfma_f32_16x16x32_bf16(qf1, ks1, sc1, 0, 0, 0);

    float madd0 = mask_t[tok0 + l16] ? 0.f : -1e30f;
    bool v0 = ((quad < 2) == (l16 < 8));
    if (!v0) madd0 = -1e30f;
    float madd1 = mask_s[b * 16 + l16] ? 0.f : -1e30f;

    // ---- softmax per row ----
    float w0[4], w1[4];
    #pragma unroll
    for (int i = 0; i < 4; ++i) {
        float a = sc0[i] * 0.125f + madd0;
        float c = sc1[i] * 0.125f + madd1;
        float mx = fmaxf(a, c);
        mx = fmaxf(mx, __shfl_xor(mx, 1));
        mx = fmaxf(mx, __shfl_xor(mx, 2));
        mx = fmaxf(mx, __shfl_xor(mx, 4));
        mx = fmaxf(mx, __shfl_xor(mx, 8));
        float e0 = __expf(a - mx), e1 = __expf(c - mx);
        float se = e0 + e1;
        se += __shfl_xor(se, 1);
        se += __shfl_xor(se, 2);
        se += __shfl_xor(se, 4);
        se += __shfl_xor(se, 8);
        float inv = 1.f / se;
        w0[i] = e0 * inv;
        w1[i] = e1 * inv;
    }

    // ---- write w_t + stage P ----
    int row0 = quad * 4;
    #pragma unroll
    for (int i = 0; i < 4; ++i) {
        int row = row0 + i;
        Pl[h][row * 40 + l16] = f2b(w0[i]);
        Pl[h][row * 40 + 16 + l16] = f2b(w1[i]);
        int s = s0 + (row >> 3), m = row & 7;
        size_t wb = ((((size_t)b * 8 + h) * 512 + s) * 8 + m) * 24;
        if (v0) w_t_out[wb + (l16 & 7)] = w0[i];
        w_t_out[wb + 8 + l16] = w1[i];
    }

    // ---- PV ----
    bf16x8 pa = *(const bf16x8*)&Pl[h][l16 * 40 + quad * 8];
    f32x4 oacc[4];
    #pragma unroll
    for (int j = 0; j < 4; ++j) {
        bf16x8 vb = *(const bf16x8*)&Vt[h][(j * 16 + l16) * 40 + quad * 8];
        oacc[j] = (f32x4){0.f, 0.f, 0.f, 0.f};
        oacc[j] = __builtin_amdgcn_mfma_f32_16x16x32_bf16(pa, vb, oacc[j], 0, 0, 0);
    }
    #pragma unroll
    for (int j = 0; j < 4; ++j)
        #pragma unroll
        for (int ii = 0; ii < 4; ++ii) {
            int row = quad * 4 + ii;
            qkv_t[(tok0 + row) * 512 + h * 64 + j * 16 + l16] = f2b(oacc[j][ii]);
        }
}

// ---------- static attention S1: fused scores + exp + PV, chunked ----------
__global__ __launch_bounds__(256) void static_attn_s1(
    const unsigned short* __restrict__ Qsp, const unsigned short* __restrict__ KH,
    const unsigned short* __restrict__ VH, const unsigned short* __restrict__ Ksp,
    const unsigned short* __restrict__ Vsp,
    const int* __restrict__ mask_t, const int* __restrict__ mask_s,
    float* __restrict__ w_s, float* __restrict__ Ppart, float* __restrict__ Lpart)
{
    int blk = blockIdx.x;
    int bh = blk & 63, c = blk >> 6;
    int b = bh >> 3, h = bh & 7;
    __shared__ __align__(16) unsigned short Klds[32 * 72];
    __shared__ __align__(16) unsigned short Vlds[64 * 40];
    __shared__ __align__(16) unsigned short Plds[16 * 40];
    __shared__ float maskv[32];
    __shared__ float sL[2][16];
    int t = threadIdx.x, wave = t >> 6, lane = t & 63, quad = lane >> 4, l16 = lane & 15;

    bf16x8 qf0 = *(const bf16x8*)(Qsp + ((size_t)(b * 16 + l16)) * 512 + h * 64 + quad * 8);
    bf16x8 qf1 = *(const bf16x8*)(Qsp + ((size_t)(b * 16 + l16)) * 512 + h * 64 + 32 + quad * 8);

    f32x4 pacc = (f32x4){0.f, 0.f, 0.f, 0.f};
    float Lacc[4] = {0.f, 0.f, 0.f, 0.f};
    int d0 = wave * 16;
    int sub = wave >> 1;
    int sr = t >> 3, spart = t & 7;
    int s0 = c * 16, s1 = (c == 7) ? 129 : (s0 + 16);

    for (int st = s0; st < s1; ++st) {
        int key0 = st * 32;
        int kk = key0 + sr;
        uint4 kv = {0, 0, 0, 0}, vv = {0, 0, 0, 0};
        if (kk < 4096) {
            kv = *(const uint4*)(KH + (((size_t)bh) * 4096 + kk) * 64 + spart * 8);
            vv = *(const uint4*)(VH + (((size_t)bh) * 4096 + kk) * 64 + spart * 8);
        } else if (kk < 4112) {
            kv = *(const uint4*)(Ksp + ((size_t)(b * 16 + kk - 4096)) * 512 + h * 64 + spart * 8);
            vv = *(const uint4*)(Vsp + ((size_t)(b * 16 + kk - 4096)) * 512 + h * 64 + spart * 8);
        }
        __syncthreads();
        *(uint4*)&Klds[sr * 72 + spart * 8] = kv;
        {
            U4 u; u.v = vv;
            #pragma unroll
            for (int ii = 0; ii < 8; ++ii) Vlds[(spart * 8 + ii) * 40 + sr] = u.u[ii];
        }
        if (t < 32) {
            int k2 = key0 + t;
            float ma = -1e30f;
            if (k2 < 4096) ma = mask_t[b * 4096 + k2] ? 0.f : -1e30f;
            else if (k2 < 4112) ma = mask_s[b * 16 + k2 - 4096] ? 0.f : -1e30f;
            maskv[t] = ma;
        }
        __syncthreads();
        if ((wave & 1) == 0) {
            bf16x8 kf0 = *(const bf16x8*)&Klds[(sub * 16 + l16) * 72 + quad * 8];
            bf16x8 kf1 = *(const bf16x8*)&Klds[(sub * 16 + l16) * 72 + 32 + quad * 8];
            f32x4 sc = (f32x4){0.f, 0.f, 0.f, 0.f};
            sc = __builtin_amdgcn_mfma_f32_16x16x32_bf16(qf0, kf0, sc, 0, 0, 0);
            sc = __builtin_amdgcn_mfma_f32_16x16x32_bf16(qf1, kf1, sc, 0, 0, 0);
            float ma = maskv[sub * 16 + l16];
            size_t wbase = (((size_t)bh) * 16 + quad * 4) * 4112 + key0 + sub * 16 + l16;
            #pragma unroll
            for (int i = 0; i < 4; ++i) {
                float sv = sc[i] * 0.125f + ma;
                float w = __expf(sv);
                Lacc[i] += w;
                w_s[wbase + (size_t)i * 4112] = w;
                Plds[(quad * 4 + i) * 40 + sub * 16 + l16] = f2b(w);
            }
        }
        __syncthreads();
        bf16x8 pf = *(const bf16x8*)&Plds[l16 * 40 + quad * 8];
        bf16x8 vf = *(const bf16x8*)&Vlds[(d0 + l16) * 40 + quad * 8];
        pacc = __builtin_amdgcn_mfma_f32_16x16x32_bf16(pf, vf, pacc, 0, 0, 0);
    }

    if ((wave & 1) == 0) {
        #pragma unroll
        for (int i = 0; i < 4; ++i) {
            float v = Lacc[i];
            v += __shfl_xor(v, 1);
            v += __shfl_xor(v, 2);
            v += __shfl_xor(v, 4);
            v += __shfl_xor(v, 8);
            Lacc[i] = v;
        }
        if (l16 == 0) {
            #pragma unroll
            for (int i = 0; i < 4; ++i) sL[wave >> 1][quad * 4 + i] = Lacc[i];
        }
    }
    size_t pbase = ((size_t)(bh * 8 + c) * 16 + quad * 4) * 64 + d0 + l16;
    #pragma unroll
    for (int i = 0; i < 4; ++i) Ppart[pbase + (size_t)i * 64] = pacc[i];
    __syncthreads();
    if (t < 16) Lpart[(bh * 8 + c) * 16 + t] = sL[0][t] + sL[1][t];
}

// ---------- static attention S4: combine chunk partials + normalize ----------
__global__ __launch_bounds__(256) void static_attn_s4(
    const float* __restrict__ Ppart, const float* __restrict__ Lpart,
    float* __restrict__ w_s, unsigned short* __restrict__ qkvS)
{
    int bh = blockIdx.x, b = bh >> 3, h = bh & 7;
    __shared__ float invL[16];
    int t = threadIdx.x;
    if (t < 16) {
        float L = 0.f;
        #pragma unroll
        for (int cc = 0; cc < 8; ++cc) L += Lpart[(bh * 8 + cc) * 16 + t];
        invL[t] = 1.f / L;
    }
    __syncthreads();
    #pragma unroll
    for (int i = 0; i < 4; ++i) {
        int idx = t + i * 256;
        int q = idx >> 6, d = idx & 63;
        float s = 0.f;
        #pragma unroll
        for (int cc = 0; cc < 8; ++cc) s += Ppart[((size_t)(bh * 8 + cc) * 16 + q) * 64 + d];
        qkvS[((size_t)(b * 16 + q)) * 512 + h * 64 + d] = f2b(s * invL[q]);
    }
    size_t base = (size_t)bh * 16 * 4112;
    for (int q = 0; q < 16; ++q) {
        float il = invL[q];
        for (int kk = t; kk < 4112; kk += 256) w_s[base + q * 4112 + kk] *= il;
    }
}

// ---------- launch ----------
extern "C" void kernel_launch(void* const* d_in, const int* in_sizes, int n_in,
                              void* d_out, int out_size, void* d_ws, size_t ws_size,
                              hipStream_t stream)
{
    const float* q_t = (const float*)d_in[0];
    const float* k_t = (const float*)d_in[1];
    const float* v_t = (const float*)d_in[2];
    const float* q_s = (const float*)d_in[3];
    const float* k_s = (const float*)d_in[4];
    const float* v_s = (const float*)d_in[5];
    const int* m_t = (const int*)d_in[6];
    const int* m_s = (const int*)d_in[7];
    const float* Wq = (const float*)d_in[8];
    const float* bq = (const float*)d_in[9];
    const float* Wk = (const float*)d_in[10];
    const float* bk = (const float*)d_in[11];
    const float* Wv = (const float*)d_in[12];
    const float* bv = (const float*)d_in[13];
    const float* Wo = (const float*)d_in[14];
    const float* bo = (const float*)d_in[15];

    char* ws = (char*)d_ws;
    size_t off = 0;
    auto alloc = [&](size_t bytes) {
        void* p = ws + off;
        off += (bytes + 255) & ~(size_t)255;
        return p;
    };
    const size_t WB = (size_t)512 * 512 * 2;     // bf16 512x512
    const size_t TB = (size_t)32768 * 512 * 2;   // bf16 32768x512
    const size_t SB = (size_t)128 * 512 * 2;     // bf16 128x512
    unsigned short* WqT = (unsigned short*)alloc(WB);
    unsigned short* WkT = (unsigned short*)alloc(WB);
    unsigned short* WvT = (unsigned short*)alloc(WB);
    unsigned short* WoT = (unsigned short*)alloc(WB);
    unsigned short* Qt   = (unsigned short*)alloc(TB);  // token-major
    unsigned short* KH   = (unsigned short*)alloc(TB);  // head-major [b][h][n][d]
    unsigned short* VH   = (unsigned short*)alloc(TB);  // head-major
    unsigned short* qkvT = (unsigned short*)alloc(TB);  // token-major
    unsigned short* Qsp  = (unsigned short*)alloc(SB);
    unsigned short* Ksp  = (unsigned short*)alloc(SB);
    unsigned short* Vsp  = (unsigned short*)alloc(SB);
    unsigned short* qkvS = (unsigned short*)alloc(SB);
    unsigned short* Qsb  = (unsigned short*)alloc(SB);  // bf16 copies of small inputs
    unsigned short* Ksb  = (unsigned short*)alloc(SB);
    unsigned short* Vsb  = (unsigned short*)alloc(SB);
    float* Ppart = (float*)alloc((size_t)64 * 8 * 16 * 64 * 4);  // [bh][chunk][q][d]
    float* Lpart = (float*)alloc((size_t)64 * 8 * 16 * 4);       // [bh][chunk][q]

    float* out    = (float*)d_out;
    float* out_tp = out;                       // [8,512,8,512]
    float* w_t_o  = out + 16777216;            // [8,8,512,8,24]
    float* out_sp = out + 23068672;            // [8,16,512]
    float* w_s_o  = out + 23134208;            // [8,8,16,4112]

    // bf16 copies of the big A matrices live in scratch that is dead until later:
    // bytes [0, 33.5M) and [33.5M, 67.1M) of d_out (out_tp region, written only by
    // the FINAL gemm), and the qkvT buffer (written only by temporal_attn).
    unsigned short* Aqb = (unsigned short*)d_out;              // 33.5 MB
    unsigned short* Akb = (unsigned short*)d_out + 16777216;   // 33.5 MB (ends at w_t_o)
    unsigned short* Avb = qkvT;                                // 33.5 MB

    cvt6<<<2048, 256, 0, stream>>>(q_t, k_t, v_t, q_s, k_s, v_s,
                                   Aqb, Akb, Avb, Qsb, Ksb, Vsb);
    transpose512cvt4<<<dim3(16, 16, 4), 256, 0, stream>>>(Wq, Wk, Wv, Wo, WqT, WkT, WvT, WoT);

    GemmSet gq  = { Aqb,  WqT, bq, Qt,   1 };
    GemmSet gk  = { Akb,  WkT, bk, KH,   2 };
    GemmSet gv  = { Avb,  WvT, bv, VH,   2 };
    GemmSet gqs = { Qsb,  WqT, bq, Qsp,  1 };
    GemmSet gks = { Ksb,  WkT, bk, Ksp,  1 };
    GemmSet gvs = { Vsb,  WvT, bv, Vsp,  1 };
    GemmSet got = { qkvT, WoT, bo, out_tp, 0 };
    GemmSet gos = { qkvS, WoT, bo, out_sp, 0 };

    // big QKV: 3 gemms x 256 m-tiles x 4 n-panels = 3072 blocks
    gemm_bf<<<dim3(3072), 256, 0, stream>>>(gq, gk, gv, 32768);
    // small QKV: 3 x 1 x 4 = 12 blocks
    gemm_bf<<<dim3(12), 256, 0, stream>>>(gqs, gks, gvs, 128);

    temporal_attn<<<2048, 512, 0, stream>>>(Qt, KH, VH, Ksp, Vsp, m_t, m_s, w_t_o, qkvT);
    static_attn_s1<<<512, 256, 0, stream>>>(Qsp, KH, VH, Ksp, Vsp, m_t, m_s, w_s_o, Ppart, Lpart);
    static_attn_s4<<<64, 256, 0, stream>>>(Ppart, Lpart, w_s_o, qkvS);

    // output projections
    gemm_bf<<<dim3(1024), 256, 0, stream>>>(got, got, got, 32768);
    gemm_bf<<<dim3(4), 256, 0, stream>>>(gos, gos, gos, 128);
}